// Round 1
// baseline (6821.624 us; speedup 1.0000x reference)
//
#include <hip/hip_runtime.h>
#include <math.h>

#define DPT 2
#define S 32
#define T 32
#define B 64
#define H 256

#define ROWS 8          // rows per block tile in cell kernels
#define RB (B / ROWS)   // row-blocks per cell
#define ROWSP 16        // rows per block in projection kernel

// ---------------- depth-0 input projections: sxw = src@W0, tyw = trg@W0 ----
__global__ __launch_bounds__(256) void proj0_kernel(
    const float* __restrict__ src, const float* __restrict__ trg,
    const float* __restrict__ W0, float* __restrict__ sxw, float* __restrict__ tyw)
{
    const int c = threadIdx.x;
    int gr0 = blockIdx.x * ROWSP;
    const float* inp; float* outp; int r0;
    if (gr0 < S * B) { inp = src; outp = sxw; r0 = gr0; }
    else             { inp = trg; outp = tyw; r0 = gr0 - S * B; }

    float acc[ROWSP];
#pragma unroll
    for (int rr = 0; rr < ROWSP; ++rr) acc[rr] = 0.f;

    for (int k = 0; k < H; ++k) {
        float wv = W0[k * H + c];
#pragma unroll
        for (int rr = 0; rr < ROWSP; ++rr)
            acc[rr] = fmaf(inp[(size_t)(r0 + rr) * H + k], wv, acc[rr]);
    }
#pragma unroll
    for (int rr = 0; rr < ROWSP; ++rr)
        outp[(size_t)(r0 + rr) * H + c] = acc[rr];
}

// ---------------- depth-0 cell wavefront ----------------
// out layout: [D][S][T][2][B][H]; ch0 = hx, ch1 = hy
__global__ __launch_bounds__(256) void cell0_kernel(
    const float* __restrict__ sxw, const float* __restrict__ tyw,
    const float* __restrict__ U0, const float* __restrict__ b0,
    float* __restrict__ out, int w)
{
    const int c    = threadIdx.x;
    const int cell = blockIdx.x / RB;
    const int rb   = blockIdx.x % RB;
    const int ilo  = (w > T - 1) ? (w - (T - 1)) : 0;
    const int i    = ilo + cell;
    const int j    = w - i;
    const int r0   = rb * ROWS;

    const float* Ut = U0;             // U[0][0:H]
    const float* Ul = U0 + H * H;     // U[0][H:2H]

    float acc[ROWS];
#pragma unroll
    for (int rr = 0; rr < ROWS; ++rr) acc[rr] = 0.f;

    if (i > 0) {
        const float* topp = out + ((((size_t)(i - 1) * T + j) * 2 + 0) * B + r0) * H;
        for (int k = 0; k < H; ++k) {
            float ut = Ut[k * H + c];
#pragma unroll
            for (int rr = 0; rr < ROWS; ++rr)
                acc[rr] = fmaf(topp[(size_t)rr * H + k], ut, acc[rr]);
        }
    }
    if (j > 0) {
        const float* lftp = out + ((((size_t)i * T + (j - 1)) * 2 + 0) * B + r0) * H;
        for (int k = 0; k < H; ++k) {
            float ul = Ul[k * H + c];
#pragma unroll
            for (int rr = 0; rr < ROWS; ++rr)
                acc[rr] = fmaf(lftp[(size_t)rr * H + k], ul, acc[rr]);
        }
    }

    const float bc = b0[c];
    const size_t obase = (((size_t)i * T + j) * 2) * (size_t)(B * H);
    const float* sx = sxw + ((size_t)i * B + r0) * H + c;
    const float* ty = tyw + ((size_t)j * B + r0) * H + c;
#pragma unroll
    for (int rr = 0; rr < ROWS; ++rr) {
        float rec = acc[rr] + bc;
        float hx = tanhf(sx[(size_t)rr * H] + rec);
        float hy = tanhf(ty[(size_t)rr * H] + rec);
        out[obase + (size_t)(r0 + rr) * H + c] = hx;
        out[obase + (size_t)(B * H) + (size_t)(r0 + rr) * H + c] = hy;
    }
}

// ---------------- depth-1 cell wavefront (input projections fused) ---------
__global__ __launch_bounds__(256) void cell1_kernel(
    const float* __restrict__ W1, const float* __restrict__ U1,
    const float* __restrict__ b1, float* __restrict__ out, int w)
{
    const int c    = threadIdx.x;
    const int cell = blockIdx.x / RB;
    const int rb   = blockIdx.x % RB;
    const int ilo  = (w > T - 1) ? (w - (T - 1)) : 0;
    const int i    = ilo + cell;
    const int j    = w - i;
    const int r0   = rb * ROWS;

    const float* Ut = U1;
    const float* Ul = U1 + H * H;
    const size_t HALF = (size_t)S * T * 2 * B * H;   // start of depth-1 block

    float acc[ROWS], xa[ROWS], ya[ROWS];
#pragma unroll
    for (int rr = 0; rr < ROWS; ++rr) { acc[rr] = 0.f; xa[rr] = 0.f; ya[rr] = 0.f; }

    // fused input projections from depth-0 outputs: xw = hx0@W1, yw = hy0@W1
    const float* hx0 = out + ((((size_t)i * T + j) * 2 + 0) * B + r0) * H;
    const float* hy0 = hx0 + (size_t)B * H;
    for (int k = 0; k < H; ++k) {
        float wv = W1[k * H + c];
#pragma unroll
        for (int rr = 0; rr < ROWS; ++rr) {
            xa[rr] = fmaf(hx0[(size_t)rr * H + k], wv, xa[rr]);
            ya[rr] = fmaf(hy0[(size_t)rr * H + k], wv, ya[rr]);
        }
    }

    if (i > 0) {
        const float* topp = out + HALF + ((((size_t)(i - 1) * T + j) * 2 + 0) * B + r0) * H;
        for (int k = 0; k < H; ++k) {
            float ut = Ut[k * H + c];
#pragma unroll
            for (int rr = 0; rr < ROWS; ++rr)
                acc[rr] = fmaf(topp[(size_t)rr * H + k], ut, acc[rr]);
        }
    }
    if (j > 0) {
        const float* lftp = out + HALF + ((((size_t)i * T + (j - 1)) * 2 + 0) * B + r0) * H;
        for (int k = 0; k < H; ++k) {
            float ul = Ul[k * H + c];
#pragma unroll
            for (int rr = 0; rr < ROWS; ++rr)
                acc[rr] = fmaf(lftp[(size_t)rr * H + k], ul, acc[rr]);
        }
    }

    const float bc = b1[c];
    const size_t obase = HALF + (((size_t)i * T + j) * 2) * (size_t)(B * H);
#pragma unroll
    for (int rr = 0; rr < ROWS; ++rr) {
        float rec = acc[rr] + bc;
        float hx = tanhf(xa[rr] + rec);
        float hy = tanhf(ya[rr] + rec);
        out[obase + (size_t)(r0 + rr) * H + c] = hx;
        out[obase + (size_t)(B * H) + (size_t)(r0 + rr) * H + c] = hy;
    }
}

extern "C" void kernel_launch(void* const* d_in, const int* in_sizes, int n_in,
                              void* d_out, int out_size, void* d_ws, size_t ws_size,
                              hipStream_t stream)
{
    const float* src = (const float*)d_in[0];
    const float* trg = (const float*)d_in[1];
    const float* W   = (const float*)d_in[2];
    const float* U   = (const float*)d_in[3];
    const float* b   = (const float*)d_in[4];
    float* out = (float*)d_out;

    // scratch for depth-0 projections: 2 * S*B*H floats = 4 MiB
    const size_t scratch_elems = (size_t)2 * S * B * H;
    float* sxw;
    if (ws_size >= scratch_elems * sizeof(float)) {
        sxw = (float*)d_ws;
    } else {
        // fall back to the front of the depth-1 output region (written only
        // by cell1 launches, which run strictly after all cell0 launches)
        sxw = out + (size_t)S * T * 2 * B * H;
    }
    float* tyw = sxw + (size_t)S * B * H;

    proj0_kernel<<<2 * S * B / ROWSP, 256, 0, stream>>>(src, trg, W, sxw, tyw);

    for (int w = 0; w < S + T - 1; ++w) {
        int ilo = (w > T - 1) ? (w - (T - 1)) : 0;
        int ihi = (w < S - 1) ? w : (S - 1);
        int ncells = ihi - ilo + 1;
        cell0_kernel<<<ncells * RB, 256, 0, stream>>>(sxw, tyw, U, b, out, w);
    }

    const float* W1 = W + H * H;
    const float* U1 = U + 2 * H * H;
    const float* b1 = b + H;
    for (int w = 0; w < S + T - 1; ++w) {
        int ilo = (w > T - 1) ? (w - (T - 1)) : 0;
        int ihi = (w < S - 1) ? w : (S - 1);
        int ncells = ihi - ilo + 1;
        cell1_kernel<<<ncells * RB, 256, 0, stream>>>(W1, U1, b1, out, w);
    }
}

// Round 2
// 1980.699 us; speedup vs baseline: 3.4440x; 3.4440x over previous
//
#include <hip/hip_runtime.h>
#include <math.h>

#define S 32
#define T 32
#define B 64
#define H 256
#define MSZ 65536   // elements per swizzled bf16 matrix [8 kt][256 col][32 kk]

typedef __attribute__((ext_vector_type(8))) short s16x8;
typedef __attribute__((ext_vector_type(4))) float f32x4;

__device__ inline unsigned short f2b(float f){
    unsigned u = __builtin_bit_cast(unsigned, f);
    u += 0x7fffu + ((u >> 16) & 1u);          // RNE
    return (unsigned short)(u >> 16);
}
__device__ inline float b2f(unsigned short s){
    unsigned u = ((unsigned)s) << 16;
    return __builtin_bit_cast(float, u);
}
__device__ inline float tanh_fast(float x){
    // tanh(x) = 1 - 2/(exp(2x)+1); exp(2x) = exp2(x * 2*log2(e))
    float e = __builtin_amdgcn_exp2f(x * 2.8853900817779268f);
    float r = __builtin_amdgcn_rcpf(e + 1.0f);
    return fmaf(-2.0f, r, 1.0f);
}
// A fragment for mfma_f32_16x16x32_bf16: lane l holds A[row = l&15][k = k0 + (l>>4)*8 + e]
__device__ inline s16x8 make_afrag(const float* __restrict__ M, int arow, int k0){
    const float* p = M + arow * H + k0;
    float4 x = *(const float4*)(p);
    float4 y = *(const float4*)(p + 4);
    s16x8 r;
    r[0]=(short)f2b(x.x); r[1]=(short)f2b(x.y); r[2]=(short)f2b(x.z); r[3]=(short)f2b(x.w);
    r[4]=(short)f2b(y.x); r[5]=(short)f2b(y.y); r[6]=(short)f2b(y.z); r[7]=(short)f2b(y.w);
    return r;
}

// ---------------- prep: swizzle U (both depths, top/left) + W[1] to bf16 ----
// Bsw[m][kt][c][kk] = M_m[kt*32+kk][c];  m: 0=U0t 1=U0l 2=U1t 3=U1l 4=W1
__global__ __launch_bounds__(256) void prep_kernel(
    const float* __restrict__ U, const float* __restrict__ W,
    unsigned short* __restrict__ Bsw)
{
    int t = blockIdx.x * 256 + threadIdx.x;
    if (t >= 5 * MSZ) return;
    int m  = t >> 16;
    int r  = t & 65535;
    int kt = r >> 13;
    int r2 = r & 8191;
    int c  = r2 >> 5;
    int kk = r2 & 31;
    int krow = kt * 32 + kk;
    float v;
    if (m < 4){ int d = m >> 1, ope = m & 1; v = U[((size_t)d*2*H + ope*H + krow)*H + c]; }
    else      { v = W[((size_t)H + krow)*H + c]; }   // W[1]
    Bsw[t] = f2b(v);
}

// ---------------- depth-0 projections (bf16 out): sxw = src@W0, tyw = trg@W0
#define ROWSP 16
__global__ __launch_bounds__(256) void proj0b_kernel(
    const float* __restrict__ src, const float* __restrict__ trg,
    const float* __restrict__ W0, unsigned short* __restrict__ sxw,
    unsigned short* __restrict__ tyw)
{
    const int c = threadIdx.x;
    int gr0 = blockIdx.x * ROWSP;
    const float* inp; unsigned short* outp; int r0;
    if (gr0 < S * B) { inp = src; outp = sxw; r0 = gr0; }
    else             { inp = trg; outp = tyw; r0 = gr0 - S * B; }

    float acc[ROWSP];
#pragma unroll
    for (int rr = 0; rr < ROWSP; ++rr) acc[rr] = 0.f;
    for (int k = 0; k < H; ++k) {
        float wv = W0[k * H + c];
#pragma unroll
        for (int rr = 0; rr < ROWSP; ++rr)
            acc[rr] = fmaf(inp[(size_t)(r0 + rr) * H + k], wv, acc[rr]);
    }
#pragma unroll
    for (int rr = 0; rr < ROWSP; ++rr)
        outp[(size_t)(r0 + rr) * H + c] = f2b(acc[rr]);
}

// ---------------- merged-wavefront MFMA stage kernel ----------------------
// stage v handles depth-0 cells with i+j==v and depth-1 cells with i+j==v-1.
// One wave (64 threads) per 16-row stripe; 4 blocks per cell.
__global__ __launch_bounds__(64) void stage_kernel(
    const unsigned short* __restrict__ Bsw,
    const unsigned short* __restrict__ sxwb,
    const unsigned short* __restrict__ tywb,
    const float* __restrict__ bvec,
    float* __restrict__ out, int v)
{
    const int lane = threadIdx.x;
    const int cellid = blockIdx.x >> 2;
    const int stripe = blockIdx.x & 3;

    int ilo0 = (v > T-1) ? v-(T-1) : 0, ihi0 = (v < S-1) ? v : S-1;
    int n0 = (v <= S+T-2) ? (ihi0 - ilo0 + 1) : 0;
    if (n0 < 0) n0 = 0;
    int w1 = v - 1;
    int ilo1 = (w1 > T-1) ? w1-(T-1) : 0;

    int d, i, j;
    if (cellid < n0) { d = 0; i = ilo0 + cellid; j = v - i; }
    else             { d = 1; int q = cellid - n0; i = ilo1 + q; j = w1 - i; }

    const int r0   = stripe * 16;
    const int arow = r0 + (lane & 15);
    const int kk0  = (lane >> 4) * 8;
    const int colq = lane & 15;
    const int rowq = r0 + ((lane >> 4) << 2);

#define OUTB(dd,ii,jj,ch) (out + ((((size_t)(dd)*S + (ii))*T + (jj))*2 + (ch)) * (size_t)(B*H))

    if (d == 0) {
        f32x4 acc[16];
#pragma unroll
        for (int t = 0; t < 16; ++t) acc[t] = (f32x4)(0.f);

        if (i > 0) {
            const float* topM = OUTB(0, i-1, j, 0);
            const unsigned short* Bt = Bsw + 0*MSZ;
            for (int kt = 0; kt < 8; ++kt) {
                s16x8 a = make_afrag(topM, arow, kt*32 + kk0);
                const unsigned short* bp = Bt + (kt*H + colq)*32 + kk0;
#pragma unroll
                for (int ct = 0; ct < 16; ++ct) {
                    s16x8 bq = *(const s16x8*)(bp + ct*512);
                    acc[ct] = __builtin_amdgcn_mfma_f32_16x16x32_bf16(a, bq, acc[ct], 0, 0, 0);
                }
            }
        }
        if (j > 0) {
            const float* lftM = OUTB(0, i, j-1, 0);
            const unsigned short* Bl = Bsw + 1*MSZ;
            for (int kt = 0; kt < 8; ++kt) {
                s16x8 a = make_afrag(lftM, arow, kt*32 + kk0);
                const unsigned short* bp = Bl + (kt*H + colq)*32 + kk0;
#pragma unroll
                for (int ct = 0; ct < 16; ++ct) {
                    s16x8 bq = *(const s16x8*)(bp + ct*512);
                    acc[ct] = __builtin_amdgcn_mfma_f32_16x16x32_bf16(a, bq, acc[ct], 0, 0, 0);
                }
            }
        }

        const unsigned short* xwp = sxwb + (size_t)i * B * H;
        const unsigned short* ywp = tywb + (size_t)j * B * H;
        float* ox = OUTB(0, i, j, 0);
        float* oy = OUTB(0, i, j, 1);
#pragma unroll
        for (int ct = 0; ct < 16; ++ct) {
            int col = ct*16 + colq;
            float bc = bvec[col];
#pragma unroll
            for (int q = 0; q < 4; ++q) {
                int row = rowq + q;
                float rec = acc[ct][q] + bc;
                float xw = b2f(xwp[row*H + col]);
                float yw = b2f(ywp[row*H + col]);
                ox[row*H + col] = tanh_fast(xw + rec);
                oy[row*H + col] = tanh_fast(yw + rec);
            }
        }
    } else {
        const float* hx0 = OUTB(0, i, j, 0);
        const float* hy0 = OUTB(0, i, j, 1);
        const float* topM = (i > 0) ? OUTB(1, i-1, j, 0) : (const float*)0;
        const float* lftM = (j > 0) ? OUTB(1, i, j-1, 0) : (const float*)0;
        const unsigned short* BU1t = Bsw + 2*MSZ;
        const unsigned short* BU1l = Bsw + 3*MSZ;
        const unsigned short* BW1  = Bsw + 4*MSZ;
        float* ox = OUTB(1, i, j, 0);
        float* oy = OUTB(1, i, j, 1);

        for (int half = 0; half < 2; ++half) {
            f32x4 ar[8], ax[8], ay[8];
#pragma unroll
            for (int t = 0; t < 8; ++t) { ar[t] = (f32x4)(0.f); ax[t] = (f32x4)(0.f); ay[t] = (f32x4)(0.f); }
            const int bbase = half*4096 + colq*32 + kk0;

            for (int kt = 0; kt < 8; ++kt) {
                const int k0 = kt*32 + kk0;
                const int bofs = kt*H*32 + bbase;
                if (topM) {
                    s16x8 a = make_afrag(topM, arow, k0);
#pragma unroll
                    for (int ct = 0; ct < 8; ++ct) {
                        s16x8 bq = *(const s16x8*)(BU1t + bofs + ct*512);
                        ar[ct] = __builtin_amdgcn_mfma_f32_16x16x32_bf16(a, bq, ar[ct], 0, 0, 0);
                    }
                }
                if (lftM) {
                    s16x8 a = make_afrag(lftM, arow, k0);
#pragma unroll
                    for (int ct = 0; ct < 8; ++ct) {
                        s16x8 bq = *(const s16x8*)(BU1l + bofs + ct*512);
                        ar[ct] = __builtin_amdgcn_mfma_f32_16x16x32_bf16(a, bq, ar[ct], 0, 0, 0);
                    }
                }
                {
                    s16x8 a = make_afrag(hx0, arow, k0);
#pragma unroll
                    for (int ct = 0; ct < 8; ++ct) {
                        s16x8 bq = *(const s16x8*)(BW1 + bofs + ct*512);
                        ax[ct] = __builtin_amdgcn_mfma_f32_16x16x32_bf16(a, bq, ax[ct], 0, 0, 0);
                    }
                }
                {
                    s16x8 a = make_afrag(hy0, arow, k0);
#pragma unroll
                    for (int ct = 0; ct < 8; ++ct) {
                        s16x8 bq = *(const s16x8*)(BW1 + bofs + ct*512);
                        ay[ct] = __builtin_amdgcn_mfma_f32_16x16x32_bf16(a, bq, ay[ct], 0, 0, 0);
                    }
                }
            }

#pragma unroll
            for (int ct = 0; ct < 8; ++ct) {
                int col = half*128 + ct*16 + colq;
                float bc = bvec[H + col];
#pragma unroll
                for (int q = 0; q < 4; ++q) {
                    int row = rowq + q;
                    float rec = ar[ct][q] + bc;
                    ox[row*H + col] = tanh_fast(ax[ct][q] + rec);
                    oy[row*H + col] = tanh_fast(ay[ct][q] + rec);
                }
            }
        }
    }
#undef OUTB
}

// =================== fp32 fallback path (round-1 kernels) ===================
#define ROWS 8
#define RB (B / ROWS)

__global__ __launch_bounds__(256) void proj0_kernel(
    const float* __restrict__ src, const float* __restrict__ trg,
    const float* __restrict__ W0, float* __restrict__ sxw, float* __restrict__ tyw)
{
    const int c = threadIdx.x;
    int gr0 = blockIdx.x * ROWSP;
    const float* inp; float* outp; int r0;
    if (gr0 < S * B) { inp = src; outp = sxw; r0 = gr0; }
    else             { inp = trg; outp = tyw; r0 = gr0 - S * B; }
    float acc[ROWSP];
#pragma unroll
    for (int rr = 0; rr < ROWSP; ++rr) acc[rr] = 0.f;
    for (int k = 0; k < H; ++k) {
        float wv = W0[k * H + c];
#pragma unroll
        for (int rr = 0; rr < ROWSP; ++rr)
            acc[rr] = fmaf(inp[(size_t)(r0 + rr) * H + k], wv, acc[rr]);
    }
#pragma unroll
    for (int rr = 0; rr < ROWSP; ++rr)
        outp[(size_t)(r0 + rr) * H + c] = acc[rr];
}

__global__ __launch_bounds__(256) void cell0_kernel(
    const float* __restrict__ sxw, const float* __restrict__ tyw,
    const float* __restrict__ U0, const float* __restrict__ b0,
    float* __restrict__ out, int w)
{
    const int c = threadIdx.x;
    const int cell = blockIdx.x / RB;
    const int rb = blockIdx.x % RB;
    const int ilo = (w > T-1) ? (w-(T-1)) : 0;
    const int i = ilo + cell, j = w - i, r0 = rb * ROWS;
    const float* Ut = U0;
    const float* Ul = U0 + H * H;
    float acc[ROWS];
#pragma unroll
    for (int rr = 0; rr < ROWS; ++rr) acc[rr] = 0.f;
    if (i > 0) {
        const float* topp = out + ((((size_t)(i-1)*T + j)*2 + 0)*B + r0)*H;
        for (int k = 0; k < H; ++k) {
            float ut = Ut[k*H + c];
#pragma unroll
            for (int rr = 0; rr < ROWS; ++rr)
                acc[rr] = fmaf(topp[(size_t)rr*H + k], ut, acc[rr]);
        }
    }
    if (j > 0) {
        const float* lftp = out + ((((size_t)i*T + (j-1))*2 + 0)*B + r0)*H;
        for (int k = 0; k < H; ++k) {
            float ul = Ul[k*H + c];
#pragma unroll
            for (int rr = 0; rr < ROWS; ++rr)
                acc[rr] = fmaf(lftp[(size_t)rr*H + k], ul, acc[rr]);
        }
    }
    const float bc = b0[c];
    const size_t obase = (((size_t)i*T + j)*2) * (size_t)(B*H);
    const float* sx = sxw + ((size_t)i*B + r0)*H + c;
    const float* ty = tyw + ((size_t)j*B + r0)*H + c;
#pragma unroll
    for (int rr = 0; rr < ROWS; ++rr) {
        float rec = acc[rr] + bc;
        out[obase + (size_t)(r0+rr)*H + c] = tanhf(sx[(size_t)rr*H] + rec);
        out[obase + (size_t)(B*H) + (size_t)(r0+rr)*H + c] = tanhf(ty[(size_t)rr*H] + rec);
    }
}

__global__ __launch_bounds__(256) void cell1_kernel(
    const float* __restrict__ W1, const float* __restrict__ U1,
    const float* __restrict__ b1, float* __restrict__ out, int w)
{
    const int c = threadIdx.x;
    const int cell = blockIdx.x / RB;
    const int rb = blockIdx.x % RB;
    const int ilo = (w > T-1) ? (w-(T-1)) : 0;
    const int i = ilo + cell, j = w - i, r0 = rb * ROWS;
    const float* Ut = U1;
    const float* Ul = U1 + H * H;
    const size_t HALF = (size_t)S * T * 2 * B * H;
    float acc[ROWS], xa[ROWS], ya[ROWS];
#pragma unroll
    for (int rr = 0; rr < ROWS; ++rr) { acc[rr]=0.f; xa[rr]=0.f; ya[rr]=0.f; }
    const float* hx0 = out + ((((size_t)i*T + j)*2 + 0)*B + r0)*H;
    const float* hy0 = hx0 + (size_t)B*H;
    for (int k = 0; k < H; ++k) {
        float wv = W1[k*H + c];
#pragma unroll
        for (int rr = 0; rr < ROWS; ++rr) {
            xa[rr] = fmaf(hx0[(size_t)rr*H + k], wv, xa[rr]);
            ya[rr] = fmaf(hy0[(size_t)rr*H + k], wv, ya[rr]);
        }
    }
    if (i > 0) {
        const float* topp = out + HALF + ((((size_t)(i-1)*T + j)*2 + 0)*B + r0)*H;
        for (int k = 0; k < H; ++k) {
            float ut = Ut[k*H + c];
#pragma unroll
            for (int rr = 0; rr < ROWS; ++rr)
                acc[rr] = fmaf(topp[(size_t)rr*H + k], ut, acc[rr]);
        }
    }
    if (j > 0) {
        const float* lftp = out + HALF + ((((size_t)i*T + (j-1))*2 + 0)*B + r0)*H;
        for (int k = 0; k < H; ++k) {
            float ul = Ul[k*H + c];
#pragma unroll
            for (int rr = 0; rr < ROWS; ++rr)
                acc[rr] = fmaf(lftp[(size_t)rr*H + k], ul, acc[rr]);
        }
    }
    const float bc = b1[c];
    const size_t obase = HALF + (((size_t)i*T + j)*2) * (size_t)(B*H);
#pragma unroll
    for (int rr = 0; rr < ROWS; ++rr) {
        float rec = acc[rr] + bc;
        out[obase + (size_t)(r0+rr)*H + c] = tanhf(xa[rr] + rec);
        out[obase + (size_t)(B*H) + (size_t)(r0+rr)*H + c] = tanhf(ya[rr] + rec);
    }
}

// ============================ host launcher ================================
extern "C" void kernel_launch(void* const* d_in, const int* in_sizes, int n_in,
                              void* d_out, int out_size, void* d_ws, size_t ws_size,
                              hipStream_t stream)
{
    const float* src = (const float*)d_in[0];
    const float* trg = (const float*)d_in[1];
    const float* W   = (const float*)d_in[2];
    const float* U   = (const float*)d_in[3];
    const float* b   = (const float*)d_in[4];
    float* out = (float*)d_out;

    const size_t need = (size_t)5*MSZ*2 + (size_t)2*S*B*H*2;  // Bsw + sxwb + tywb
    if (ws_size >= need) {
        unsigned short* Bsw  = (unsigned short*)d_ws;
        unsigned short* sxwb = Bsw + (size_t)5*MSZ;
        unsigned short* tywb = sxwb + (size_t)S*B*H;

        prep_kernel<<<(5*MSZ + 255)/256, 256, 0, stream>>>(U, W, Bsw);
        proj0b_kernel<<<2*S*B/ROWSP, 256, 0, stream>>>(src, trg, W, sxwb, tywb);

        for (int v = 0; v < S + T; ++v) {
            int ilo0 = (v > T-1) ? v-(T-1) : 0, ihi0 = (v < S-1) ? v : S-1;
            int n0 = (v <= S+T-2) ? (ihi0 - ilo0 + 1) : 0;
            if (n0 < 0) n0 = 0;
            int n1 = 0;
            int w1 = v - 1;
            if (w1 >= 0) {
                int ilo1 = (w1 > T-1) ? w1-(T-1) : 0, ihi1 = (w1 < S-1) ? w1 : S-1;
                n1 = ihi1 - ilo1 + 1;
            }
            stage_kernel<<<4*(n0+n1), 64, 0, stream>>>(Bsw, sxwb, tywb, b, out, v);
        }
        return;
    }

    // -------- fp32 fallback (round-1 structure) --------
    const size_t scratch_elems = (size_t)2 * S * B * H;
    float* sxw;
    if (ws_size >= scratch_elems * sizeof(float)) sxw = (float*)d_ws;
    else sxw = out + (size_t)S * T * 2 * B * H;
    float* tyw = sxw + (size_t)S * B * H;

    proj0_kernel<<<2*S*B/ROWSP, 256, 0, stream>>>(src, trg, W, sxw, tyw);
    for (int w = 0; w < S + T - 1; ++w) {
        int ilo = (w > T-1) ? (w-(T-1)) : 0, ihi = (w < S-1) ? w : (S-1);
        cell0_kernel<<<(ihi-ilo+1)*RB, 256, 0, stream>>>(sxw, tyw, U, b, out, w);
    }
    const float* W1 = W + H*H;
    const float* U1 = U + 2*H*H;
    const float* b1 = b + H;
    for (int w = 0; w < S + T - 1; ++w) {
        int ilo = (w > T-1) ? (w-(T-1)) : 0, ihi = (w < S-1) ? w : (S-1);
        cell1_kernel<<<(ihi-ilo+1)*RB, 256, 0, stream>>>(W1, U1, b1, out, w);
    }
}

// Round 3
// 1109.368 us; speedup vs baseline: 6.1491x; 1.7854x over previous
//
#include <hip/hip_runtime.h>
#include <math.h>

#define S 32
#define T 32
#define B 64
#define H 256
#define MSZ 65536   // elements per swizzled bf16 matrix [8 kt][256 col][32 kk]
#define ROWSP 16

typedef __attribute__((ext_vector_type(8))) short s16x8;
typedef __attribute__((ext_vector_type(4))) float f32x4;

__device__ inline unsigned short f2b(float f){
    unsigned u = __builtin_bit_cast(unsigned, f);
    u += 0x7fffu + ((u >> 16) & 1u);          // RNE
    return (unsigned short)(u >> 16);
}
__device__ inline float b2f(unsigned short s){
    unsigned u = ((unsigned)s) << 16;
    return __builtin_bit_cast(float, u);
}
__device__ inline float tanh_fast(float x){
    float e = __builtin_amdgcn_exp2f(x * 2.8853900817779268f);
    float r = __builtin_amdgcn_rcpf(e + 1.0f);
    return fmaf(-2.0f, r, 1.0f);
}
__device__ inline void waitflag(int* f, int target){
    while (__hip_atomic_load(f, __ATOMIC_RELAXED, __HIP_MEMORY_SCOPE_AGENT) < target)
        __builtin_amdgcn_s_sleep(2);
    (void)__hip_atomic_load(f, __ATOMIC_ACQUIRE, __HIP_MEMORY_SCOPE_AGENT);
}

// ---------------- prep: swizzle U (both depths, top/left) + W[1] to bf16 ----
// Bsw[m][kt][c][kk] = M_m[kt*32+kk][c];  m: 0=U0t 1=U0l 2=U1t 3=U1l 4=W1
__global__ __launch_bounds__(256) void prep_kernel(
    const float* __restrict__ U, const float* __restrict__ W,
    unsigned short* __restrict__ Bsw)
{
    int t = blockIdx.x * 256 + threadIdx.x;
    if (t >= 5 * MSZ) return;
    int m  = t >> 16;
    int r  = t & 65535;
    int kt = r >> 13;
    int r2 = r & 8191;
    int c  = r2 >> 5;
    int kk = r2 & 31;
    int krow = kt * 32 + kk;
    float v;
    if (m < 4){ int d = m >> 1, ope = m & 1; v = U[((size_t)d*2*H + ope*H + krow)*H + c]; }
    else      { v = W[((size_t)H + krow)*H + c]; }   // W[1]
    Bsw[t] = f2b(v);
}

// ---------------- depth-0 projections (bf16 out): sxw = src@W0, tyw = trg@W0
__global__ __launch_bounds__(256) void proj0b_kernel(
    const float* __restrict__ src, const float* __restrict__ trg,
    const float* __restrict__ W0, unsigned short* __restrict__ sxw,
    unsigned short* __restrict__ tyw)
{
    const int c = threadIdx.x;
    int gr0 = blockIdx.x * ROWSP;
    const float* inp; unsigned short* outp; int r0;
    if (gr0 < S * B) { inp = src; outp = sxw; r0 = gr0; }
    else             { inp = trg; outp = tyw; r0 = gr0 - S * B; }

    float acc[ROWSP];
#pragma unroll
    for (int rr = 0; rr < ROWSP; ++rr) acc[rr] = 0.f;
    for (int k = 0; k < H; ++k) {
        float wv = W0[k * H + c];
#pragma unroll
        for (int rr = 0; rr < ROWSP; ++rr)
            acc[rr] = fmaf(inp[(size_t)(r0 + rr) * H + k], wv, acc[rr]);
    }
#pragma unroll
    for (int rr = 0; rr < ROWSP; ++rr)
        outp[(size_t)(r0 + rr) * H + c] = f2b(acc[rr]);
}

__global__ __launch_bounds__(256) void zeroflags_kernel(int* flags, int n){
    int t = blockIdx.x * 256 + threadIdx.x;
    if (t < n) flags[t] = 0;
}

// ---------------- persistent dataflow grid kernel ----------------
// 128 blocks: blk 0..63 = depth0 (row=blk>>1, half=blk&1), 64..127 = depth1.
// Block walks j=0..31; flags flag0/flag1 count completed col-halves (target 2).
__global__ __launch_bounds__(512, 2) void grid_kernel(
    const unsigned short* __restrict__ Bsw,
    const unsigned short* __restrict__ sxwb,
    const unsigned short* __restrict__ tywb,
    const float* __restrict__ bvec,
    float* __restrict__ out,
    int* __restrict__ flags)
{
    __shared__ unsigned short Alds[4 * 64 * 128];   // 64 KB: [op][row 64][k 128] bf16 (XOR-swizzled)
    char* AldsB = (char*)Alds;

    const int blk   = blockIdx.x;
    const int depth = blk >> 6;
    const int i     = (blk & 63) >> 1;
    const int half  = blk & 1;
    const int c0    = half * 128;

    const int tid  = threadIdx.x;
    const int lane = tid & 63;
    const int wv   = tid >> 6;          // wave 0..7, owns 16 cols
    const int colq = lane & 15;
    const int hi   = lane >> 4;
    const int kk0  = hi * 8;
    const int col  = c0 + wv * 16 + colq;
    const int hi16 = hi * 16;
    const int lswz = (colq & 7) << 4;   // A-frag read swizzle (row&7 == colq&7)

    const int row64 = tid >> 3;         // staging row 0..63
    const int k4b   = (tid & 7) * 4;    // staging float4 base within 32
    const int swz   = (row64 & 7) << 4; // staging write swizzle

    int* flag0 = flags;
    int* flag1 = flags + S * T;

    // persistent B fragments in VGPRs
    s16x8 bfT[8], bfL[8], bfW[8];
    {
        const unsigned short* mT = Bsw + (size_t)(depth == 0 ? 0 : 2) * MSZ;
        const unsigned short* mL = Bsw + (size_t)(depth == 0 ? 1 : 3) * MSZ;
        const unsigned short* mW = Bsw + (size_t)4 * MSZ;
#pragma unroll
        for (int kt = 0; kt < 8; ++kt) {
            int o = (kt * H + col) * 32 + kk0;
            bfT[kt] = *(const s16x8*)(mT + o);
            bfL[kt] = *(const s16x8*)(mL + o);
            bfW[kt] = *(const s16x8*)(mW + o);
        }
    }

    const size_t CH = (size_t)B * H;
#define OPTR(dd,ii,jj,ch) (out + ((((size_t)(dd)*S + (ii))*T + (jj))*2 + (ch)) * CH)

#define LOADOP(OP, SP, KC) do { \
    const float* _s = (SP); \
    if (_s) { const float* _p = _s + (size_t)row64 * H + (KC)*128 + k4b*4; \
        L[(OP)*4+0] = *(const float4*)(_p); \
        L[(OP)*4+1] = *(const float4*)(_p + 4); \
        L[(OP)*4+2] = *(const float4*)(_p + 8); \
        L[(OP)*4+3] = *(const float4*)(_p + 12); } \
    else { float4 _z = {0.f,0.f,0.f,0.f}; \
        L[(OP)*4+0]=_z; L[(OP)*4+1]=_z; L[(OP)*4+2]=_z; L[(OP)*4+3]=_z; } \
} while(0)

#define WRITEOP(OP) do { \
    _Pragma("unroll") \
    for (int _l = 0; _l < 4; ++_l) { \
        float4 _v = L[(OP)*4+_l]; \
        uint2 _u; \
        _u.x = f2b(_v.x) | ((unsigned)f2b(_v.y) << 16); \
        _u.y = f2b(_v.z) | ((unsigned)f2b(_v.w) << 16); \
        *(uint2*)(AldsB + (OP)*16384 + row64*256 + (((k4b+_l)*8) ^ swz)) = _u; \
    } \
} while(0)

#define AFRAG(OP, RT, KTL) (*(const s16x8*)(AldsB + (OP)*16384 + ((RT)*16 + colq)*256 + ((((KTL)*64) + hi16) ^ lswz)))

    for (int j = 0; j < T; ++j) {
        if (tid == 0) {
            if (depth == 0) {
                if (i > 0) waitflag(&flag0[(i-1)*T + j], 2);
                if (j > 0) waitflag(&flag0[i*T + (j-1)], 2);
            } else {
                waitflag(&flag0[i*T + j], 2);
                if (i > 0) waitflag(&flag1[(i-1)*T + j], 2);
                if (j > 0) waitflag(&flag1[i*T + (j-1)], 2);
            }
        }
        __syncthreads();

        const float* sTop  = nullptr;
        const float* sLeft = nullptr;
        const float* sHx0  = nullptr;
        const float* sHy0  = nullptr;
        if (depth == 0) {
            if (i > 0) sTop  = OPTR(0, i-1, j, 0);
            if (j > 0) sLeft = OPTR(0, i, j-1, 0);
        } else {
            if (i > 0) sTop  = OPTR(1, i-1, j, 0);
            if (j > 0) sLeft = OPTR(1, i, j-1, 0);
            sHx0 = OPTR(0, i, j, 0);
            sHy0 = OPTR(0, i, j, 1);
        }

        f32x4 ar[4], ax[4], ay[4];
#pragma unroll
        for (int rt = 0; rt < 4; ++rt){ ar[rt] = (f32x4)(0.f); ax[rt] = (f32x4)(0.f); ay[rt] = (f32x4)(0.f); }

        float4 L[16];

        if (depth == 0) {
            LOADOP(0, sTop, 0); LOADOP(1, sLeft, 0);
            WRITEOP(0); WRITEOP(1);
            __syncthreads();
            LOADOP(0, sTop, 1); LOADOP(1, sLeft, 1);     // prefetch chunk 1
#pragma unroll
            for (int ktl = 0; ktl < 4; ++ktl)
#pragma unroll
                for (int rt = 0; rt < 4; ++rt) {
                    ar[rt] = __builtin_amdgcn_mfma_f32_16x16x32_bf16(AFRAG(0,rt,ktl), bfT[ktl], ar[rt], 0, 0, 0);
                    ar[rt] = __builtin_amdgcn_mfma_f32_16x16x32_bf16(AFRAG(1,rt,ktl), bfL[ktl], ar[rt], 0, 0, 0);
                }
            __syncthreads();
            WRITEOP(0); WRITEOP(1);
            __syncthreads();
#pragma unroll
            for (int ktl = 0; ktl < 4; ++ktl)
#pragma unroll
                for (int rt = 0; rt < 4; ++rt) {
                    ar[rt] = __builtin_amdgcn_mfma_f32_16x16x32_bf16(AFRAG(0,rt,ktl), bfT[4+ktl], ar[rt], 0, 0, 0);
                    ar[rt] = __builtin_amdgcn_mfma_f32_16x16x32_bf16(AFRAG(1,rt,ktl), bfL[4+ktl], ar[rt], 0, 0, 0);
                }
            __syncthreads();

            const unsigned short* xwp = sxwb + (size_t)i * B * H;
            const unsigned short* ywp = tywb + (size_t)j * B * H;
            float* ox = OPTR(0, i, j, 0);
            float* oy = OPTR(0, i, j, 1);
            float bb = bvec[col];
#pragma unroll
            for (int rt = 0; rt < 4; ++rt)
#pragma unroll
                for (int q = 0; q < 4; ++q) {
                    int row = rt*16 + hi*4 + q;
                    float rec = ar[rt][q] + bb;
                    float hx = tanh_fast(b2f(xwp[row*H + col]) + rec);
                    float hy = tanh_fast(b2f(ywp[row*H + col]) + rec);
                    __hip_atomic_store(&ox[row*H + col], hx, __ATOMIC_RELAXED, __HIP_MEMORY_SCOPE_AGENT);
                    __hip_atomic_store(&oy[row*H + col], hy, __ATOMIC_RELAXED, __HIP_MEMORY_SCOPE_AGENT);
                }
        } else {
            LOADOP(0, sTop, 0); LOADOP(1, sLeft, 0); LOADOP(2, sHx0, 0); LOADOP(3, sHy0, 0);
            WRITEOP(0); WRITEOP(1); WRITEOP(2); WRITEOP(3);
            __syncthreads();
            LOADOP(0, sTop, 1); LOADOP(1, sLeft, 1); LOADOP(2, sHx0, 1); LOADOP(3, sHy0, 1);
#pragma unroll
            for (int ktl = 0; ktl < 4; ++ktl)
#pragma unroll
                for (int rt = 0; rt < 4; ++rt) {
                    ar[rt] = __builtin_amdgcn_mfma_f32_16x16x32_bf16(AFRAG(0,rt,ktl), bfT[ktl], ar[rt], 0, 0, 0);
                    ar[rt] = __builtin_amdgcn_mfma_f32_16x16x32_bf16(AFRAG(1,rt,ktl), bfL[ktl], ar[rt], 0, 0, 0);
                    ax[rt] = __builtin_amdgcn_mfma_f32_16x16x32_bf16(AFRAG(2,rt,ktl), bfW[ktl], ax[rt], 0, 0, 0);
                    ay[rt] = __builtin_amdgcn_mfma_f32_16x16x32_bf16(AFRAG(3,rt,ktl), bfW[ktl], ay[rt], 0, 0, 0);
                }
            __syncthreads();
            WRITEOP(0); WRITEOP(1); WRITEOP(2); WRITEOP(3);
            __syncthreads();
#pragma unroll
            for (int ktl = 0; ktl < 4; ++ktl)
#pragma unroll
                for (int rt = 0; rt < 4; ++rt) {
                    ar[rt] = __builtin_amdgcn_mfma_f32_16x16x32_bf16(AFRAG(0,rt,ktl), bfT[4+ktl], ar[rt], 0, 0, 0);
                    ar[rt] = __builtin_amdgcn_mfma_f32_16x16x32_bf16(AFRAG(1,rt,ktl), bfL[4+ktl], ar[rt], 0, 0, 0);
                    ax[rt] = __builtin_amdgcn_mfma_f32_16x16x32_bf16(AFRAG(2,rt,ktl), bfW[4+ktl], ax[rt], 0, 0, 0);
                    ay[rt] = __builtin_amdgcn_mfma_f32_16x16x32_bf16(AFRAG(3,rt,ktl), bfW[4+ktl], ay[rt], 0, 0, 0);
                }
            __syncthreads();

            float* ox = OPTR(1, i, j, 0);
            float* oy = OPTR(1, i, j, 1);
            float bb = bvec[H + col];
#pragma unroll
            for (int rt = 0; rt < 4; ++rt)
#pragma unroll
                for (int q = 0; q < 4; ++q) {
                    int row = rt*16 + hi*4 + q;
                    float rec = ar[rt][q] + bb;
                    float hx = tanh_fast(ax[rt][q] + rec);
                    float hy = tanh_fast(ay[rt][q] + rec);
                    __hip_atomic_store(&ox[row*H + col], hx, __ATOMIC_RELAXED, __HIP_MEMORY_SCOPE_AGENT);
                    __hip_atomic_store(&oy[row*H + col], hy, __ATOMIC_RELAXED, __HIP_MEMORY_SCOPE_AGENT);
                }
        }

        // publish
        asm volatile("s_waitcnt vmcnt(0)" ::: "memory");
        __syncthreads();
        if (tid == 0) {
            int* f = (depth == 0) ? &flag0[i*T + j] : &flag1[i*T + j];
            __hip_atomic_fetch_add(f, 1, __ATOMIC_RELEASE, __HIP_MEMORY_SCOPE_AGENT);
        }
    }
#undef OPTR
#undef LOADOP
#undef WRITEOP
#undef AFRAG
}

// =================== round-2 staged fallback ===================
__device__ inline s16x8 make_afrag(const float* __restrict__ M, int arow, int k0){
    const float* p = M + arow * H + k0;
    float4 x = *(const float4*)(p);
    float4 y = *(const float4*)(p + 4);
    s16x8 r;
    r[0]=(short)f2b(x.x); r[1]=(short)f2b(x.y); r[2]=(short)f2b(x.z); r[3]=(short)f2b(x.w);
    r[4]=(short)f2b(y.x); r[5]=(short)f2b(y.y); r[6]=(short)f2b(y.z); r[7]=(short)f2b(y.w);
    return r;
}

__global__ __launch_bounds__(64) void stage_kernel(
    const unsigned short* __restrict__ Bsw,
    const unsigned short* __restrict__ sxwb,
    const unsigned short* __restrict__ tywb,
    const float* __restrict__ bvec,
    float* __restrict__ out, int v)
{
    const int lane = threadIdx.x;
    const int cellid = blockIdx.x >> 2;
    const int stripe = blockIdx.x & 3;

    int ilo0 = (v > T-1) ? v-(T-1) : 0, ihi0 = (v < S-1) ? v : S-1;
    int n0 = (v <= S+T-2) ? (ihi0 - ilo0 + 1) : 0;
    if (n0 < 0) n0 = 0;
    int w1 = v - 1;
    int ilo1 = (w1 > T-1) ? w1-(T-1) : 0;

    int d, i, j;
    if (cellid < n0) { d = 0; i = ilo0 + cellid; j = v - i; }
    else             { d = 1; int q = cellid - n0; i = ilo1 + q; j = w1 - i; }

    const int r0   = stripe * 16;
    const int arow = r0 + (lane & 15);
    const int kk0  = (lane >> 4) * 8;
    const int colq = lane & 15;
    const int rowq = r0 + ((lane >> 4) << 2);

#define OUTB(dd,ii,jj,ch) (out + ((((size_t)(dd)*S + (ii))*T + (jj))*2 + (ch)) * (size_t)(B*H))

    if (d == 0) {
        f32x4 acc[16];
#pragma unroll
        for (int t = 0; t < 16; ++t) acc[t] = (f32x4)(0.f);
        if (i > 0) {
            const float* topM = OUTB(0, i-1, j, 0);
            const unsigned short* Bt = Bsw + 0*MSZ;
            for (int kt = 0; kt < 8; ++kt) {
                s16x8 a = make_afrag(topM, arow, kt*32 + kk0);
                const unsigned short* bp = Bt + (kt*H + colq)*32 + kk0;
#pragma unroll
                for (int ct = 0; ct < 16; ++ct) {
                    s16x8 bq = *(const s16x8*)(bp + ct*512);
                    acc[ct] = __builtin_amdgcn_mfma_f32_16x16x32_bf16(a, bq, acc[ct], 0, 0, 0);
                }
            }
        }
        if (j > 0) {
            const float* lftM = OUTB(0, i, j-1, 0);
            const unsigned short* Bl = Bsw + 1*MSZ;
            for (int kt = 0; kt < 8; ++kt) {
                s16x8 a = make_afrag(lftM, arow, kt*32 + kk0);
                const unsigned short* bp = Bl + (kt*H + colq)*32 + kk0;
#pragma unroll
                for (int ct = 0; ct < 16; ++ct) {
                    s16x8 bq = *(const s16x8*)(bp + ct*512);
                    acc[ct] = __builtin_amdgcn_mfma_f32_16x16x32_bf16(a, bq, acc[ct], 0, 0, 0);
                }
            }
        }
        const unsigned short* xwp = sxwb + (size_t)i * B * H;
        const unsigned short* ywp = tywb + (size_t)j * B * H;
        float* ox = OUTB(0, i, j, 0);
        float* oy = OUTB(0, i, j, 1);
#pragma unroll
        for (int ct = 0; ct < 16; ++ct) {
            int col = ct*16 + colq;
            float bc = bvec[col];
#pragma unroll
            for (int q = 0; q < 4; ++q) {
                int row = rowq + q;
                float rec = acc[ct][q] + bc;
                ox[row*H + col] = tanh_fast(b2f(xwp[row*H + col]) + rec);
                oy[row*H + col] = tanh_fast(b2f(ywp[row*H + col]) + rec);
            }
        }
    } else {
        const float* hx0 = OUTB(0, i, j, 0);
        const float* hy0 = OUTB(0, i, j, 1);
        const float* topM = (i > 0) ? OUTB(1, i-1, j, 0) : (const float*)0;
        const float* lftM = (j > 0) ? OUTB(1, i, j-1, 0) : (const float*)0;
        const unsigned short* BU1t = Bsw + 2*MSZ;
        const unsigned short* BU1l = Bsw + 3*MSZ;
        const unsigned short* BW1  = Bsw + 4*MSZ;
        float* ox = OUTB(1, i, j, 0);
        float* oy = OUTB(1, i, j, 1);

        for (int halfc = 0; halfc < 2; ++halfc) {
            f32x4 arr[8], axx[8], ayy[8];
#pragma unroll
            for (int t = 0; t < 8; ++t) { arr[t] = (f32x4)(0.f); axx[t] = (f32x4)(0.f); ayy[t] = (f32x4)(0.f); }
            const int bbase = halfc*4096 + colq*32 + kk0;

            for (int kt = 0; kt < 8; ++kt) {
                const int k0 = kt*32 + kk0;
                const int bofs = kt*H*32 + bbase;
                if (topM) {
                    s16x8 a = make_afrag(topM, arow, k0);
#pragma unroll
                    for (int ct = 0; ct < 8; ++ct)
                        arr[ct] = __builtin_amdgcn_mfma_f32_16x16x32_bf16(a, *(const s16x8*)(BU1t + bofs + ct*512), arr[ct], 0, 0, 0);
                }
                if (lftM) {
                    s16x8 a = make_afrag(lftM, arow, k0);
#pragma unroll
                    for (int ct = 0; ct < 8; ++ct)
                        arr[ct] = __builtin_amdgcn_mfma_f32_16x16x32_bf16(a, *(const s16x8*)(BU1l + bofs + ct*512), arr[ct], 0, 0, 0);
                }
                {
                    s16x8 a = make_afrag(hx0, arow, k0);
#pragma unroll
                    for (int ct = 0; ct < 8; ++ct)
                        axx[ct] = __builtin_amdgcn_mfma_f32_16x16x32_bf16(a, *(const s16x8*)(BW1 + bofs + ct*512), axx[ct], 0, 0, 0);
                }
                {
                    s16x8 a = make_afrag(hy0, arow, k0);
#pragma unroll
                    for (int ct = 0; ct < 8; ++ct)
                        ayy[ct] = __builtin_amdgcn_mfma_f32_16x16x32_bf16(a, *(const s16x8*)(BW1 + bofs + ct*512), ayy[ct], 0, 0, 0);
                }
            }
#pragma unroll
            for (int ct = 0; ct < 8; ++ct) {
                int col = halfc*128 + ct*16 + colq;
                float bc = bvec[H + col];
#pragma unroll
                for (int q = 0; q < 4; ++q) {
                    int row = rowq + q;
                    float rec = arr[ct][q] + bc;
                    ox[row*H + col] = tanh_fast(axx[ct][q] + rec);
                    oy[row*H + col] = tanh_fast(ayy[ct][q] + rec);
                }
            }
        }
    }
#undef OUTB
}

// ============================ host launcher ================================
extern "C" void kernel_launch(void* const* d_in, const int* in_sizes, int n_in,
                              void* d_out, int out_size, void* d_ws, size_t ws_size,
                              hipStream_t stream)
{
    const float* src = (const float*)d_in[0];
    const float* trg = (const float*)d_in[1];
    const float* W   = (const float*)d_in[2];
    const float* U   = (const float*)d_in[3];
    const float* b   = (const float*)d_in[4];
    float* out = (float*)d_out;

    const size_t need_stage   = (size_t)5*MSZ*2 + (size_t)2*S*B*H*2;            // 2,752,512
    const size_t need_persist = need_stage + (size_t)2*S*T*sizeof(int);          // +8 KB flags

    unsigned short* Bsw  = (unsigned short*)d_ws;
    unsigned short* sxwb = Bsw + (size_t)5*MSZ;
    unsigned short* tywb = sxwb + (size_t)S*B*H;
    int* flags = (int*)(tywb + (size_t)S*B*H);

    if (ws_size >= need_persist) {
        prep_kernel<<<(5*MSZ + 255)/256, 256, 0, stream>>>(U, W, Bsw);
        proj0b_kernel<<<2*S*B/ROWSP, 256, 0, stream>>>(src, trg, W, sxwb, tywb);
        zeroflags_kernel<<<(2*S*T + 255)/256, 256, 0, stream>>>(flags, 2*S*T);
        grid_kernel<<<128, 512, 0, stream>>>(Bsw, sxwb, tywb, b, out, flags);
        return;
    }

    // -------- round-2 staged fallback --------
    prep_kernel<<<(5*MSZ + 255)/256, 256, 0, stream>>>(U, W, Bsw);
    proj0b_kernel<<<2*S*B/ROWSP, 256, 0, stream>>>(src, trg, W, sxwb, tywb);
    for (int v = 0; v < S + T; ++v) {
        int ilo0 = (v > T-1) ? v-(T-1) : 0, ihi0 = (v < S-1) ? v : S-1;
        int n0 = (v <= S+T-2) ? (ihi0 - ilo0 + 1) : 0;
        if (n0 < 0) n0 = 0;
        int n1 = 0;
        int w1 = v - 1;
        if (w1 >= 0) {
            int ilo1 = (w1 > T-1) ? w1-(T-1) : 0, ihi1 = (w1 < S-1) ? w1 : S-1;
            n1 = ihi1 - ilo1 + 1;
        }
        stage_kernel<<<4*(n0+n1), 64, 0, stream>>>(Bsw, sxwb, tywb, b, out, v);
    }
}